// Round 11
// baseline (2003.736 us; speedup 1.0000x reference)
//
#include <hip/hip_runtime.h>

#define S_    1024
#define NT_   258
#define TG_   256
#define LN2f  0.69314718056f
#define RSTR4 272           // state row stride in bf16 elems; dword-stride 136 == 8 mod 32
#define BUF4  (4*RSTR4)     // elems per state buffer (4 batch rows)

typedef __attribute__((ext_vector_type(8))) short bf8_t;   // 8 bf16 (4 VGPR) MFMA A/B frag
typedef __attribute__((ext_vector_type(4))) float f4_t;    // MFMA C/D frag

__device__ __forceinline__ unsigned short f2bf(float f) {
  unsigned u = __float_as_uint(f);
  u += 0x7fffu + ((u >> 16) & 1u);          // RTNE
  return (unsigned short)(u >> 16);
}
__device__ __forceinline__ float bf2f(unsigned s) {        // low 16 bits
  return __uint_as_float(s << 16);
}
__device__ __forceinline__ unsigned pk_bf16(float lo, float hi) {
  unsigned d;
  asm("v_cvt_pk_bf16_f32 %0, %1, %2" : "=v"(d) : "v"(lo), "v"(hi));
  return d;
}

// ===========================================================================
// ANSWER PATH — Round-9 scan4 verbatim (PASSED absmax 0.0, 706us).
// ===========================================================================
__global__ __launch_bounds__(512, 2) void crf_scan4(
    const float* __restrict__ logits, const float* __restrict__ trans,
    const int* __restrict__ y, float* __restrict__ ws)
{
  __shared__ __align__(16) unsigned short aL[2*BUF4];
  __shared__ __align__(16) int   earr[4];
  __shared__ float esumL[4];
  __shared__ float refL[4];

  const int tid = threadIdx.x;
  const int w  = tid >> 6;
  const int l  = tid & 63;
  const int bq = blockIdx.x * 4;
  const int lg = l >> 4;
  const int lc = l & 15;

  bf8_t Bf0[8], Bf1[8];
#pragma unroll
  for (int kk = 0; kk < 8; ++kk) {
    bf8_t b0, b1;
    const int n = 32*w + 2*lc;
#pragma unroll
    for (int e = 0; e < 8; ++e) {
      const int k = kk*32 + lg*8 + e;
      b0[e] = (short)f2bf(__expf(trans[k*NT_ + n]));
      b1[e] = (short)f2bf(__expf(trans[k*NT_ + n + 1]));
    }
    Bf0[kk] = b0; Bf1[kk] = b1;
  }

  const int idxA0 = (lc & 3)*RSTR4 + lg*8;
  int idxW_r[4], embase_r[4], ybase[4];
#pragma unroll
  for (int r = 0; r < 4; ++r) {
    idxW_r[r]   = r*RSTR4 + 32*w + 2*lc;
    embase_r[r] = (bq + r)*(S_*256) + 32*w + 2*lc;
    ybase[r]    = (bq + r)*S_;
  }

  {
    if (tid < 4) {
      refL[tid]  = logits[(size_t)(bq + tid)*(S_*256)] + trans[TG_*NT_];
      esumL[tid] = 0.f;
    }
    __syncthreads();
    if (tid < 128) {
      const int bi = tid >> 5;
      const int cb = (tid & 31) * 8;
      const float ref = refL[bi];
      uint2 dd;
      {
        const float4 em = *(const float4*)&logits[(size_t)(bq + bi)*(S_*256) + cb];
        const float4 ts = *(const float4*)&trans[TG_*NT_ + cb];
        dd.x = pk_bf16(__expf(em.x + ts.x - ref), __expf(em.y + ts.y - ref));
        dd.y = pk_bf16(__expf(em.z + ts.z - ref), __expf(em.w + ts.w - ref));
      }
      *(uint2*)&aL[bi*RSTR4 + cb] = dd;
      {
        const float4 em = *(const float4*)&logits[(size_t)(bq + bi)*(S_*256) + cb + 4];
        const float4 ts = *(const float4*)&trans[TG_*NT_ + cb + 4];
        dd.x = pk_bf16(__expf(em.x + ts.x - ref), __expf(em.y + ts.y - ref));
        dd.y = pk_bf16(__expf(em.z + ts.z - ref), __expf(em.w + ts.w - ref));
      }
      *(uint2*)&aL[bi*RSTR4 + cb + 4] = dd;
    }
  }

  float2 emA[4], emB[4];
  int yA[4], yB[4];
#pragma unroll
  for (int r = 0; r < 4; ++r) {
    yA[r] = y[ybase[r] + 1];
    yB[r] = y[ybase[r] + 2];
    emA[r] = *(const float2*)&logits[embase_r[r] + 1*256];
    emB[r] = *(const float2*)&logits[embase_r[r] + 2*256];
  }
  float esv[4] = {0.f, 0.f, 0.f, 0.f};

  __syncthreads();

#define SCAN_STEP(T_, CURE_, NXTE_, EMV_, YV_) do {                           \
  bf8_t Af_[8];                                                               \
  _Pragma("unroll") for (int kk = 0; kk < 8; ++kk)                            \
    Af_[kk] = *(const bf8_t*)&aL[(CURE_) + idxA0 + 32*kk];                    \
  float F0_[4], F1_[4]; int m_[4];                                            \
  _Pragma("unroll") for (int r = 0; r < 4; ++r) {                             \
    m_[r] = YV_[r];                                                           \
    F0_[r] = __expf(EMV_[r].x); F1_[r] = __expf(EMV_[r].y); }                 \
  const int tp_ = ((T_)+2 < S_) ? ((T_)+2) : (S_-1);                          \
  _Pragma("unroll") for (int r = 0; r < 4; ++r) {                             \
    YV_[r] = y[ybase[r] + tp_];                                               \
    EMV_[r] = *(const float2*)&logits[embase_r[r] + tp_*256]; }               \
  f4_t c0_ = {0.f,0.f,0.f,0.f}, c1_ = {0.f,0.f,0.f,0.f};                      \
  _Pragma("unroll") for (int kk = 0; kk < 8; ++kk) {                          \
    c0_ = __builtin_amdgcn_mfma_f32_16x16x32_bf16(Af_[kk], Bf0[kk], c0_, 0, 0, 0); \
    c1_ = __builtin_amdgcn_mfma_f32_16x16x32_bf16(Af_[kk], Bf1[kk], c1_, 0, 0, 0); } \
  float v0_[4], v1_[4];                                                       \
  _Pragma("unroll") for (int r = 0; r < 4; ++r) {                             \
    v0_[r] = F0_[r]*c0_[r]; v1_[r] = F1_[r]*c1_[r]; }                         \
  if (((T_) & 7) == 0) {                                                      \
    const int4 er_ = *(const int4*)&earr[0];                                  \
    v0_[0] = ldexpf(v0_[0], -er_.x); v1_[0] = ldexpf(v1_[0], -er_.x);         \
    v0_[1] = ldexpf(v0_[1], -er_.y); v1_[1] = ldexpf(v1_[1], -er_.y);         \
    v0_[2] = ldexpf(v0_[2], -er_.z); v1_[2] = ldexpf(v1_[2], -er_.z);         \
    v0_[3] = ldexpf(v0_[3], -er_.w); v1_[3] = ldexpf(v1_[3], -er_.w);         \
    if (w == 0 && l == 0) {                                                   \
      if (m_[0] >= 0) esv[0] += (float)er_.x;                                 \
      if (m_[1] >= 0) esv[1] += (float)er_.y;                                 \
      if (m_[2] >= 0) esv[2] += (float)er_.z;                                 \
      if (m_[3] >= 0) esv[3] += (float)er_.w; } }                             \
  if (lg == 0) {                                                              \
    _Pragma("unroll") for (int r = 0; r < 4; ++r) {                           \
      unsigned d_ = pk_bf16(v0_[r], v1_[r]);                                  \
      const unsigned old_ = *(const unsigned*)&aL[(CURE_) + idxW_r[r]];       \
      if (m_[r] < 0) d_ = old_;                                               \
      *(unsigned*)&aL[(NXTE_) + idxW_r[r]] = d_; } }                          \
  if (((T_) & 7) == 7 && w == 0 && l == 0) {                                  \
    _Pragma("unroll") for (int r = 0; r < 4; ++r)                             \
      earr[r] = (int)((__float_as_uint(v0_[r]) >> 23) & 255) - 127; }         \
  asm volatile("s_waitcnt lgkmcnt(0)\n\ts_barrier" ::: "memory");             \
  __builtin_amdgcn_sched_barrier(0);                                          \
} while (0)

  SCAN_STEP(1, 0, BUF4, emA, yA);
#pragma unroll 1
  for (int tt = 2; tt < S_; tt += 2) {
    SCAN_STEP(tt,   BUF4, 0, emB, yB);
    SCAN_STEP(tt+1, 0, BUF4, emA, yA);
  }
#undef SCAN_STEP

  if (w == 0 && l == 0) {
#pragma unroll
    for (int r = 0; r < 4; ++r) esumL[r] = esv[r];
  }
  __syncthreads();
  if (tid < 128) {
    const int bi = tid >> 5, j0 = (tid & 31) * 8;
    float p = 0.f;
#pragma unroll
    for (int e = 0; e < 8; ++e) {
      const int k = j0 + e;
      p += bf2f(aL[BUF4 + bi*RSTR4 + k]) * __expf(trans[k*NT_ + 257]);
    }
#pragma unroll
    for (int o = 16; o; o >>= 1) p += __shfl_xor(p, o, 32);
    if ((tid & 31) == 0)
      ws[128 + bq + bi] = __logf(p) + esumL[bi]*LN2f + refL[bi];
  }
}

// ===========================================================================
// DIAGNOSTIC CLONES — timing-only (rocprof per-dispatch). Outputs go to dead
// ws scratch (>=384) which crf_fin never reads. Structure mirrors crf_scan4.
// MODE 0 (diagA): no in-loop VMEM (F=1, length-register freeze).
// MODE 1 (diagB): A + MFMA replaced by cheap VALU chain on loaded frags.
// MODE 2 (diagC): A + no inter-wave barrier (lgkmcnt only).
// ===========================================================================
template <int MODE>
__global__ __launch_bounds__(512, 2) void crf_diag(
    const float* __restrict__ logits, const float* __restrict__ trans,
    const int* __restrict__ y, float* __restrict__ ws)
{
  __shared__ __align__(16) unsigned short aL[2*BUF4];
  __shared__ __align__(16) int   earr[4];
  __shared__ float esumL[4];
  __shared__ float refL[4];
  __shared__ int   lenL[4];

  const int tid = threadIdx.x;
  const int w  = tid >> 6;
  const int l  = tid & 63;
  const int bq = blockIdx.x * 4;
  const int lg = l >> 4;
  const int lc = l & 15;

  bf8_t Bf0[8], Bf1[8];
#pragma unroll
  for (int kk = 0; kk < 8; ++kk) {
    bf8_t b0, b1;
    const int n = 32*w + 2*lc;
#pragma unroll
    for (int e = 0; e < 8; ++e) {
      const int k = kk*32 + lg*8 + e;
      b0[e] = (short)f2bf(__expf(trans[k*NT_ + n]));
      b1[e] = (short)f2bf(__expf(trans[k*NT_ + n + 1]));
    }
    Bf0[kk] = b0; Bf1[kk] = b1;
  }

  const int idxA0 = (lc & 3)*RSTR4 + lg*8;
  int idxW_r[4];
#pragma unroll
  for (int r = 0; r < 4; ++r) idxW_r[r] = r*RSTR4 + 32*w + 2*lc;

  if (tid < 4) {
    refL[tid]  = logits[(size_t)(bq + tid)*(S_*256)] + trans[TG_*NT_];
    esumL[tid] = 0.f;
    earr[tid]  = 0;
  }
  if (w < 4) {                      // wave w counts batch w's length
    const int4* yp = (const int4*)&y[(bq + w) * S_];
    int c = 0;
#pragma unroll
    for (int i = 0; i < 4; ++i) {
      const int4 v = yp[l*4 + i];
      c += (v.x >= 0) + (v.y >= 0) + (v.z >= 0) + (v.w >= 0);
    }
#pragma unroll
    for (int o = 32; o; o >>= 1) c += __shfl_xor(c, o);
    if (l == 0) lenL[w] = c;
  }
  __syncthreads();
  if (tid < 128) {
    const int bi = tid >> 5;
    const int cb = (tid & 31) * 8;
    const float ref = refL[bi];
    uint2 dd;
    {
      const float4 em = *(const float4*)&logits[(size_t)(bq + bi)*(S_*256) + cb];
      const float4 ts = *(const float4*)&trans[TG_*NT_ + cb];
      dd.x = pk_bf16(__expf(em.x + ts.x - ref), __expf(em.y + ts.y - ref));
      dd.y = pk_bf16(__expf(em.z + ts.z - ref), __expf(em.w + ts.w - ref));
    }
    *(uint2*)&aL[bi*RSTR4 + cb] = dd;
    {
      const float4 em = *(const float4*)&logits[(size_t)(bq + bi)*(S_*256) + cb + 4];
      const float4 ts = *(const float4*)&trans[TG_*NT_ + cb + 4];
      dd.x = pk_bf16(__expf(em.x + ts.x - ref), __expf(em.y + ts.y - ref));
      dd.y = pk_bf16(__expf(em.z + ts.z - ref), __expf(em.w + ts.w - ref));
    }
    *(uint2*)&aL[bi*RSTR4 + cb + 4] = dd;
  }
  __syncthreads();
  int lenm1_r[4];
#pragma unroll
  for (int r = 0; r < 4; ++r) lenm1_r[r] = lenL[r] - 1;

  float esv[4] = {0.f, 0.f, 0.f, 0.f};

#define DIAG_STEP(T_, CURE_, NXTE_) do {                                      \
  bf8_t Af_[8];                                                               \
  _Pragma("unroll") for (int kk = 0; kk < 8; ++kk)                            \
    Af_[kk] = *(const bf8_t*)&aL[(CURE_) + idxA0 + 32*kk];                    \
  float v0_[4], v1_[4];                                                       \
  if (MODE == 1) {        /* cheap VALU stand-in keeps frag reads live */     \
    float acc_ = 0.f;                                                         \
    _Pragma("unroll") for (int kk = 0; kk < 8; ++kk)                          \
      acc_ += (float)Af_[kk][0] + (float)Af_[kk][7];                          \
    _Pragma("unroll") for (int r = 0; r < 4; ++r) { v0_[r] = acc_; v1_[r] = acc_; } \
  } else {                                                                    \
    f4_t c0_ = {0.f,0.f,0.f,0.f}, c1_ = {0.f,0.f,0.f,0.f};                    \
    _Pragma("unroll") for (int kk = 0; kk < 8; ++kk) {                        \
      c0_ = __builtin_amdgcn_mfma_f32_16x16x32_bf16(Af_[kk], Bf0[kk], c0_, 0, 0, 0); \
      c1_ = __builtin_amdgcn_mfma_f32_16x16x32_bf16(Af_[kk], Bf1[kk], c1_, 0, 0, 0); } \
    _Pragma("unroll") for (int r = 0; r < 4; ++r) { v0_[r] = c0_[r]; v1_[r] = c1_[r]; } \
  }                                                                           \
  if (((T_) & 7) == 0) {                                                      \
    const int4 er_ = *(const int4*)&earr[0];                                  \
    v0_[0] = ldexpf(v0_[0], -er_.x); v1_[0] = ldexpf(v1_[0], -er_.x);         \
    v0_[1] = ldexpf(v0_[1], -er_.y); v1_[1] = ldexpf(v1_[1], -er_.y);         \
    v0_[2] = ldexpf(v0_[2], -er_.z); v1_[2] = ldexpf(v1_[2], -er_.z);         \
    v0_[3] = ldexpf(v0_[3], -er_.w); v1_[3] = ldexpf(v1_[3], -er_.w);         \
    if (w == 0 && l == 0) {                                                   \
      if ((T_) <= lenm1_r[0]) esv[0] += (float)er_.x;                         \
      if ((T_) <= lenm1_r[1]) esv[1] += (float)er_.y;                         \
      if ((T_) <= lenm1_r[2]) esv[2] += (float)er_.z;                         \
      if ((T_) <= lenm1_r[3]) esv[3] += (float)er_.w; } }                     \
  if (lg == 0) {                                                              \
    _Pragma("unroll") for (int r = 0; r < 4; ++r) {                           \
      unsigned d_ = pk_bf16(v0_[r], v1_[r]);                                  \
      const unsigned old_ = *(const unsigned*)&aL[(CURE_) + idxW_r[r]];       \
      if ((T_) > lenm1_r[r]) d_ = old_;                                       \
      *(unsigned*)&aL[(NXTE_) + idxW_r[r]] = d_; } }                          \
  if (((T_) & 7) == 7 && w == 0 && l == 0) {                                  \
    _Pragma("unroll") for (int r = 0; r < 4; ++r)                             \
      earr[r] = (int)((__float_as_uint(v0_[r]) >> 23) & 255) - 127; }         \
  if (MODE == 2) {                                                            \
    asm volatile("s_waitcnt lgkmcnt(0)" ::: "memory");                        \
  } else {                                                                    \
    asm volatile("s_waitcnt lgkmcnt(0)\n\ts_barrier" ::: "memory");           \
  }                                                                           \
  __builtin_amdgcn_sched_barrier(0);                                          \
} while (0)

#pragma unroll 1
  for (int t = 1; t <= 1021; t += 2) {
    DIAG_STEP(t,     0,    BUF4);
    DIAG_STEP(t + 1, BUF4, 0);
  }
  DIAG_STEP(1023, 0, BUF4);
#undef DIAG_STEP

  if (w == 0 && l == 0) {
#pragma unroll
    for (int r = 0; r < 4; ++r) esumL[r] = esv[r];
  }
  __syncthreads();
  if (tid < 128) {
    const int bi = tid >> 5, j0 = (tid & 31) * 8;
    float p = 0.f;
#pragma unroll
    for (int e = 0; e < 8; ++e) {
      const int k = j0 + e;
      p += bf2f(aL[BUF4 + bi*RSTR4 + k]) * __expf(trans[k*NT_ + 257]);
    }
#pragma unroll
    for (int o = 16; o; o >>= 1) p += __shfl_xor(p, o, 32);
    if ((tid & 31) == 0)
      ws[384 + 128*MODE + bq + bi] = __logf(fabsf(p) + 1e-30f) + esumL[bi]*LN2f + refL[bi];
  }
}

// ---------------------------------------------------------------------------
// llh (gold-path score) + lengths: 128 blocks x 256 threads, t-parallel.
// ---------------------------------------------------------------------------
__global__ void crf_llh(const float* __restrict__ logits, const float* __restrict__ trans,
                        const int* __restrict__ y, float* __restrict__ ws)
{
  const int b = blockIdx.x, tid = threadIdx.x;
  const int yb = b * S_;
  float part = 0.f; int cnt = 0;
  for (int t = tid; t < S_; t += 256) {
    const int yt = y[yb + t];
    const bool m = (yt >= 0);
    if (m) ++cnt;
    if (t == 0) {
      const int tag0 = m ? yt : 0;
      part += trans[TG_*NT_ + tag0];
      if (m) part += logits[(size_t)yb * 256 + tag0];
    } else if (m) {
      const int yp = y[yb + t - 1];
      part += logits[((size_t)(yb + t)) * 256 + yt] + trans[yp*NT_ + yt];
    }
    if (m && (t + 1 == S_ || y[yb + t + 1] < 0))
      part += trans[yt*NT_ + 257];
  }
#pragma unroll
  for (int o = 32; o; o >>= 1) { part += __shfl_xor(part, o); cnt += __shfl_xor(cnt, o); }
  __shared__ float sp[4]; __shared__ int sc[4];
  if ((tid & 63) == 0) { sp[tid >> 6] = part; sc[tid >> 6] = cnt; }
  __syncthreads();
  if (tid == 0) {
    ws[b]       = sp[0] + sp[1] + sp[2] + sp[3];
    ws[256 + b] = (float)(sc[0] + sc[1] + sc[2] + sc[3]);
  }
}

// ---------------------------------------------------------------------------
// loss = mean_b( -(llh - log_z)/len )   (reads only ws[0..384))
// ---------------------------------------------------------------------------
__global__ void crf_fin(const float* __restrict__ ws, float* __restrict__ out)
{
  const int i = threadIdx.x;  // 128
  float v = -(ws[i] - ws[128 + i]) / ws[256 + i];
#pragma unroll
  for (int o = 32; o; o >>= 1) v += __shfl_xor(v, o);
  __shared__ float s2[2];
  if ((i & 63) == 0) s2[i >> 6] = v;
  __syncthreads();
  if (i == 0) out[0] = (s2[0] + s2[1]) * (1.0f / 128.0f);
}

extern "C" void kernel_launch(void* const* d_in, const int* in_sizes, int n_in,
                              void* d_out, int out_size, void* d_ws, size_t ws_size,
                              hipStream_t stream)
{
  const float* logits = (const float*)d_in[0];
  const float* trans  = (const float*)d_in[1];
  const int*   y      = (const int*)d_in[2];
  float* ws  = (float*)d_ws;   // [0,128) llh | [128,256) log_z | [256,384) len | >=384 diag scratch
  float* out = (float*)d_out;

  hipLaunchKernelGGL(crf_llh,     dim3(128), dim3(256), 0, stream, logits, trans, y, ws);
  hipLaunchKernelGGL(crf_scan4,   dim3(32),  dim3(512), 0, stream, logits, trans, y, ws);
  hipLaunchKernelGGL((crf_diag<0>), dim3(32), dim3(512), 0, stream, logits, trans, y, ws);
  hipLaunchKernelGGL((crf_diag<1>), dim3(32), dim3(512), 0, stream, logits, trans, y, ws);
  hipLaunchKernelGGL((crf_diag<2>), dim3(32), dim3(512), 0, stream, logits, trans, y, ws);
  hipLaunchKernelGGL(crf_fin,     dim3(1),   dim3(128), 0, stream, ws, out);
}

// Round 12
// 964.152 us; speedup vs baseline: 2.0782x; 2.0782x over previous
//
#include <hip/hip_runtime.h>

#define S_    1024
#define NT_   258
#define TG_   256
#define LN2f  0.69314718056f
#define RSTR4 272           // state row stride in bf16 elems; dword-stride 136 == 8 mod 32
#define BUF4  (4*RSTR4)     // elems per state buffer (4 batch rows)

typedef __attribute__((ext_vector_type(8))) short bf8_t;   // 8 bf16 (4 VGPR) MFMA A/B frag
typedef __attribute__((ext_vector_type(4))) float f4_t;    // MFMA C/D frag

__device__ __forceinline__ unsigned short f2bf(float f) {
  unsigned u = __float_as_uint(f);
  u += 0x7fffu + ((u >> 16) & 1u);          // RTNE
  return (unsigned short)(u >> 16);
}
__device__ __forceinline__ float bf2f(unsigned s) {        // low 16 bits
  return __uint_as_float(s << 16);
}
__device__ __forceinline__ unsigned pk_bf16(float lo, float hi) {
  unsigned d;
  asm("v_cvt_pk_bf16_f32 %0, %1, %2" : "=v"(d) : "v"(lo), "v"(hi));
  return d;
}

// step body shared by answer + diag. BAR_=1 emits the fused waitcnt+s_barrier,
// BAR_=0 waitcnt only (diag measures the no-barrier step time).
// MFMA: 8 independent depth-2 chains (4/column) + tree reduce — cuts the
// dependent-MFMA chain from depth 8 to depth 2 (R11 diag: chain ~470cy).
#define SCAN_STEP_G(T_, CURE_, NXTE_, EMV_, YV_, BAR_) do {                   \
  bf8_t Af_[8];                                                               \
  _Pragma("unroll") for (int kk = 0; kk < 8; ++kk)                            \
    Af_[kk] = *(const bf8_t*)&aL[(CURE_) + idxA0 + 32*kk];                    \
  float F0_[4], F1_[4]; int m_[4];                                            \
  _Pragma("unroll") for (int r = 0; r < 4; ++r) {                             \
    m_[r] = YV_[r];                                                           \
    F0_[r] = __expf(EMV_[r].x); F1_[r] = __expf(EMV_[r].y); }                 \
  const int tp_ = ((T_)+4 < S_) ? ((T_)+4) : (S_-1);                          \
  _Pragma("unroll") for (int r = 0; r < 4; ++r) {                             \
    YV_[r] = y[ybase[r] + tp_];                                               \
    EMV_[r] = *(const float2*)&logits[embase_r[r] + (size_t)tp_*256]; }       \
  f4_t c0_[4], c1_[4];                                                        \
  _Pragma("unroll") for (int q = 0; q < 4; ++q) {                             \
    c0_[q] = __builtin_amdgcn_mfma_f32_16x16x32_bf16(Af_[2*q],   Bf0[2*q],   zf4, 0, 0, 0); \
    c0_[q] = __builtin_amdgcn_mfma_f32_16x16x32_bf16(Af_[2*q+1], Bf0[2*q+1], c0_[q], 0, 0, 0); \
    c1_[q] = __builtin_amdgcn_mfma_f32_16x16x32_bf16(Af_[2*q],   Bf1[2*q],   zf4, 0, 0, 0); \
    c1_[q] = __builtin_amdgcn_mfma_f32_16x16x32_bf16(Af_[2*q+1], Bf1[2*q+1], c1_[q], 0, 0, 0); } \
  const f4_t s0_ = (c0_[0] + c0_[1]) + (c0_[2] + c0_[3]);                     \
  const f4_t s1_ = (c1_[0] + c1_[1]) + (c1_[2] + c1_[3]);                     \
  float v0_[4], v1_[4];                                                       \
  _Pragma("unroll") for (int r = 0; r < 4; ++r) {                             \
    v0_[r] = F0_[r]*s0_[r]; v1_[r] = F1_[r]*s1_[r]; }                         \
  if (((T_) & 7) == 0) {                    /* apply rescale published T-1 */ \
    const int4 er_ = *(const int4*)&earr[0];                                  \
    v0_[0] = ldexpf(v0_[0], -er_.x); v1_[0] = ldexpf(v1_[0], -er_.x);         \
    v0_[1] = ldexpf(v0_[1], -er_.y); v1_[1] = ldexpf(v1_[1], -er_.y);         \
    v0_[2] = ldexpf(v0_[2], -er_.z); v1_[2] = ldexpf(v1_[2], -er_.z);         \
    v0_[3] = ldexpf(v0_[3], -er_.w); v1_[3] = ldexpf(v1_[3], -er_.w);         \
    if (w == 0 && l == 0) {                                                   \
      if (m_[0] >= 0) esv[0] += (float)er_.x;                                 \
      if (m_[1] >= 0) esv[1] += (float)er_.y;                                 \
      if (m_[2] >= 0) esv[2] += (float)er_.z;                                 \
      if (m_[3] >= 0) esv[3] += (float)er_.w; } }                             \
  if (lg == 0) {                            /* 16 lanes write 4 rows */       \
    _Pragma("unroll") for (int r = 0; r < 4; ++r) {                           \
      unsigned d_ = pk_bf16(v0_[r], v1_[r]);                                  \
      const unsigned old_ = *(const unsigned*)&aL[(CURE_) + idxW_r[r]];       \
      if (m_[r] < 0) d_ = old_;             /* frozen rows carry exact */     \
      *(unsigned*)&aL[(NXTE_) + idxW_r[r]] = d_; } }                          \
  if (((T_) & 7) == 7 && w == 0 && l == 0) {   /* publish exponent of a[b][0] */ \
    _Pragma("unroll") for (int r = 0; r < 4; ++r)                             \
      earr[r] = (int)((__float_as_uint(v0_[r]) >> 23) & 255) - 127; }         \
  if (BAR_) { asm volatile("s_waitcnt lgkmcnt(0)\n\ts_barrier" ::: "memory"); } \
  else      { asm volatile("s_waitcnt lgkmcnt(0)" ::: "memory"); }            \
  __builtin_amdgcn_sched_barrier(0);                                          \
} while (0)

// shared prologue: B preload, addresses, t=0 init, em/y distance-4 prefetch
#define SCAN_PROLOGUE()                                                       \
  const int tid = threadIdx.x;                                                \
  const int w  = tid >> 6;                                                    \
  const int l  = tid & 63;                                                    \
  const int bq = blockIdx.x * 4;                                              \
  const int lg = l >> 4;                                                      \
  const int lc = l & 15;                                                      \
  const f4_t zf4 = {0.f, 0.f, 0.f, 0.f};                                      \
  bf8_t Bf0[8], Bf1[8];                                                       \
  _Pragma("unroll")                                                           \
  for (int kk = 0; kk < 8; ++kk) {                                            \
    bf8_t b0, b1;                                                             \
    const int n = 32*w + 2*lc;                                                \
    _Pragma("unroll")                                                         \
    for (int e = 0; e < 8; ++e) {                                             \
      const int k = kk*32 + lg*8 + e;                                         \
      b0[e] = (short)f2bf(__expf(trans[k*NT_ + n]));                          \
      b1[e] = (short)f2bf(__expf(trans[k*NT_ + n + 1]));                      \
    }                                                                         \
    Bf0[kk] = b0; Bf1[kk] = b1;                                               \
  }                                                                           \
  const int idxA0 = (lc & 3)*RSTR4 + lg*8;                                    \
  int idxW_r[4], embase_r[4], ybase[4];                                       \
  _Pragma("unroll")                                                           \
  for (int r = 0; r < 4; ++r) {                                               \
    idxW_r[r]   = r*RSTR4 + 32*w + 2*lc;                                      \
    embase_r[r] = (bq + r)*(S_*256) + 32*w + 2*lc;                            \
    ybase[r]    = (bq + r)*S_;                                                \
  }                                                                           \
  {                                                                           \
    if (tid < 4) {                                                            \
      refL[tid]  = logits[(size_t)(bq + tid)*(S_*256)] + trans[TG_*NT_];      \
      esumL[tid] = 0.f;                                                       \
      earr[tid]  = 0;                                                         \
    }                                                                         \
    __syncthreads();                                                          \
    if (tid < 128) {                                                          \
      const int bi = tid >> 5;                                                \
      const int cb = (tid & 31) * 8;                                          \
      const float ref = refL[bi];                                             \
      uint2 dd;                                                               \
      {                                                                       \
        const float4 em = *(const float4*)&logits[(size_t)(bq + bi)*(S_*256) + cb]; \
        const float4 ts = *(const float4*)&trans[TG_*NT_ + cb];               \
        dd.x = pk_bf16(__expf(em.x + ts.x - ref), __expf(em.y + ts.y - ref)); \
        dd.y = pk_bf16(__expf(em.z + ts.z - ref), __expf(em.w + ts.w - ref)); \
      }                                                                       \
      *(uint2*)&aL[bi*RSTR4 + cb] = dd;                                       \
      {                                                                       \
        const float4 em = *(const float4*)&logits[(size_t)(bq + bi)*(S_*256) + cb + 4]; \
        const float4 ts = *(const float4*)&trans[TG_*NT_ + cb + 4];           \
        dd.x = pk_bf16(__expf(em.x + ts.x - ref), __expf(em.y + ts.y - ref)); \
        dd.y = pk_bf16(__expf(em.z + ts.z - ref), __expf(em.w + ts.w - ref)); \
      }                                                                       \
      *(uint2*)&aL[bi*RSTR4 + cb + 4] = dd;                                   \
    }                                                                         \
  }                                                                           \
  float2 emA[4], emB[4], emC[4], emD[4];                                      \
  int yA[4], yB[4], yC[4], yD[4];                                             \
  _Pragma("unroll")                                                           \
  for (int r = 0; r < 4; ++r) {                                               \
    yA[r] = y[ybase[r] + 1];  emA[r] = *(const float2*)&logits[embase_r[r] + 1*256]; \
    yB[r] = y[ybase[r] + 2];  emB[r] = *(const float2*)&logits[embase_r[r] + 2*256]; \
    yC[r] = y[ybase[r] + 3];  emC[r] = *(const float2*)&logits[embase_r[r] + 3*256]; \
    yD[r] = y[ybase[r] + 4];  emD[r] = *(const float2*)&logits[embase_r[r] + 4*256]; \
  }                                                                           \
  float esv[4] = {0.f, 0.f, 0.f, 0.f};                                        \
  __syncthreads();

// ---------------------------------------------------------------------------
// ANSWER scan: R9 semantics verbatim; perf changes: 8x depth-2 MFMA chains
// + tree reduce (f32 reassociation only), em/y prefetch distance 4.
// ---------------------------------------------------------------------------
__global__ __launch_bounds__(512, 2) void crf_scan4(
    const float* __restrict__ logits, const float* __restrict__ trans,
    const int* __restrict__ y, float* __restrict__ ws)
{
  __shared__ __align__(16) unsigned short aL[2*BUF4];
  __shared__ __align__(16) int   earr[4];
  __shared__ float esumL[4];
  __shared__ float refL[4];

  SCAN_PROLOGUE()

#pragma unroll 1
  for (int t = 1; t <= 1017; t += 4) {
    SCAN_STEP_G(t,     0,     BUF4, emA, yA, 1);
    SCAN_STEP_G(t + 1, BUF4,  0,    emB, yB, 1);
    SCAN_STEP_G(t + 2, 0,     BUF4, emC, yC, 1);
    SCAN_STEP_G(t + 3, BUF4,  0,    emD, yD, 1);
  }
  SCAN_STEP_G(1021, 0,    BUF4, emA, yA, 1);
  SCAN_STEP_G(1022, BUF4, 0,    emB, yB, 1);
  SCAN_STEP_G(1023, 0,    BUF4, emC, yC, 1);

  // ---- finalize: log_z[b] = log( sum_j a[b][j]*exp(T[j,END]) ) + esum*ln2 + ref
  if (w == 0 && l == 0) {
#pragma unroll
    for (int r = 0; r < 4; ++r) esumL[r] = esv[r];
  }
  __syncthreads();
  if (tid < 128) {
    const int bi = tid >> 5, j0 = (tid & 31) * 8;
    float p = 0.f;
#pragma unroll
    for (int e = 0; e < 8; ++e) {
      const int k = j0 + e;
      p += bf2f(aL[BUF4 + bi*RSTR4 + k]) * __expf(trans[k*NT_ + 257]);
    }
#pragma unroll
    for (int o = 16; o; o >>= 1) p += __shfl_xor(p, o, 32);
    if ((tid & 31) == 0)
      ws[128 + bq + bi] = __logf(p) + esumL[bi]*LN2f + refL[bi];
  }
}

// ---------------------------------------------------------------------------
// DIAGNOSTIC: same step body, NO barrier, 512 steps, dead output (ws>=512).
// Recovered from dur_us total: dnb = total - scan4 - llh - fin. Measures the
// no-sync step floor (issue + latency chain) of the NEW step body.
// ---------------------------------------------------------------------------
__global__ __launch_bounds__(512, 2) void crf_dnb(
    const float* __restrict__ logits, const float* __restrict__ trans,
    const int* __restrict__ y, float* __restrict__ ws)
{
  __shared__ __align__(16) unsigned short aL[2*BUF4];
  __shared__ __align__(16) int   earr[4];
  __shared__ float esumL[4];
  __shared__ float refL[4];

  SCAN_PROLOGUE()

#pragma unroll 1
  for (int t = 1; t <= 509; t += 4) {       // 512 steps, no barrier
    SCAN_STEP_G(t,     0,     BUF4, emA, yA, 0);
    SCAN_STEP_G(t + 1, BUF4,  0,    emB, yB, 0);
    SCAN_STEP_G(t + 2, 0,     BUF4, emC, yC, 0);
    SCAN_STEP_G(t + 3, BUF4,  0,    emD, yD, 0);
  }

  if (w == 0 && l == 0) {
#pragma unroll
    for (int r = 0; r < 4; ++r) esumL[r] = esv[r];
  }
  __syncthreads();
  if (tid < 128) {
    const int bi = tid >> 5, j0 = (tid & 31) * 8;
    float p = 0.f;
#pragma unroll
    for (int e = 0; e < 8; ++e) {
      const int k = j0 + e;
      p += bf2f(aL[BUF4 + bi*RSTR4 + k]) * __expf(trans[k*NT_ + 257]);
    }
#pragma unroll
    for (int o = 16; o; o >>= 1) p += __shfl_xor(p, o, 32);
    if ((tid & 31) == 0)
      ws[512 + bq + bi] = __logf(fabsf(p) + 1e-30f) + esumL[bi]*LN2f + refL[bi];
  }
}

// ---------------------------------------------------------------------------
// llh (gold-path score) + lengths: 128 blocks x 256 threads, t-parallel.
// ---------------------------------------------------------------------------
__global__ void crf_llh(const float* __restrict__ logits, const float* __restrict__ trans,
                        const int* __restrict__ y, float* __restrict__ ws)
{
  const int b = blockIdx.x, tid = threadIdx.x;
  const int yb = b * S_;
  float part = 0.f; int cnt = 0;
  for (int t = tid; t < S_; t += 256) {
    const int yt = y[yb + t];
    const bool m = (yt >= 0);
    if (m) ++cnt;
    if (t == 0) {
      const int tag0 = m ? yt : 0;
      part += trans[TG_*NT_ + tag0];                       // T[START, y0]
      if (m) part += logits[(size_t)yb * 256 + tag0];
    } else if (m) {
      const int yp = y[yb + t - 1];                        // mask monotone => valid
      part += logits[((size_t)(yb + t)) * 256 + yt] + trans[yp*NT_ + yt];
    }
    if (m && (t + 1 == S_ || y[yb + t + 1] < 0))
      part += trans[yt*NT_ + 257];                         // T[last, END]
  }
#pragma unroll
  for (int o = 32; o; o >>= 1) { part += __shfl_xor(part, o); cnt += __shfl_xor(cnt, o); }
  __shared__ float sp[4]; __shared__ int sc[4];
  if ((tid & 63) == 0) { sp[tid >> 6] = part; sc[tid >> 6] = cnt; }
  __syncthreads();
  if (tid == 0) {
    ws[b]       = sp[0] + sp[1] + sp[2] + sp[3];
    ws[256 + b] = (float)(sc[0] + sc[1] + sc[2] + sc[3]);
  }
}

// ---------------------------------------------------------------------------
// loss = mean_b( -(llh - log_z)/len )   (reads only ws[0..384))
// ---------------------------------------------------------------------------
__global__ void crf_fin(const float* __restrict__ ws, float* __restrict__ out)
{
  const int i = threadIdx.x;  // 128
  float v = -(ws[i] - ws[128 + i]) / ws[256 + i];
#pragma unroll
  for (int o = 32; o; o >>= 1) v += __shfl_xor(v, o);
  __shared__ float s2[2];
  if ((i & 63) == 0) s2[i >> 6] = v;
  __syncthreads();
  if (i == 0) out[0] = (s2[0] + s2[1]) * (1.0f / 128.0f);
}

extern "C" void kernel_launch(void* const* d_in, const int* in_sizes, int n_in,
                              void* d_out, int out_size, void* d_ws, size_t ws_size,
                              hipStream_t stream)
{
  const float* logits = (const float*)d_in[0];
  const float* trans  = (const float*)d_in[1];
  const int*   y      = (const int*)d_in[2];
  float* ws  = (float*)d_ws;   // [0,128) llh | [128,256) log_z | [256,384) len | >=512 diag scratch
  float* out = (float*)d_out;

  hipLaunchKernelGGL(crf_llh,   dim3(128), dim3(256), 0, stream, logits, trans, y, ws);
  hipLaunchKernelGGL(crf_scan4, dim3(32),  dim3(512), 0, stream, logits, trans, y, ws);
  hipLaunchKernelGGL(crf_dnb,   dim3(32),  dim3(512), 0, stream, logits, trans, y, ws);
  hipLaunchKernelGGL(crf_fin,   dim3(1),   dim3(128), 0, stream, ws, out);
}

// Round 15
// 678.690 us; speedup vs baseline: 2.9524x; 1.4206x over previous
//
#include <hip/hip_runtime.h>

#define S_    1024
#define NT_   258
#define TG_   256
#define LN2f  0.69314718056f
#define RSTR4 272           // state row stride in bf16 elems; dword-stride 136 == 8 mod 32
#define BUF4  (4*RSTR4)     // elems per state buffer (4 batch rows)

typedef __attribute__((ext_vector_type(8))) short bf8_t;   // 8 bf16 (4 VGPR) MFMA A/B frag
typedef __attribute__((ext_vector_type(4))) float f4_t;    // MFMA C/D frag

__device__ __forceinline__ unsigned short f2bf(float f) {
  unsigned u = __float_as_uint(f);
  u += 0x7fffu + ((u >> 16) & 1u);          // RTNE
  return (unsigned short)(u >> 16);
}
__device__ __forceinline__ float bf2f(unsigned s) {        // low 16 bits
  return __uint_as_float(s << 16);
}
__device__ __forceinline__ unsigned pk_bf16(float lo, float hi) {
  unsigned d;
  asm("v_cvt_pk_bf16_f32 %0, %1, %2" : "=v"(d) : "v"(lo), "v"(hi));
  return d;
}

// ---------------------------------------------------------------------------
// Scan: 32 blocks (4 batches each) x 512 threads (8 waves, 2/SIMD).
// Verified R12 answer path (PASSED absmax 0.0, scan 677us profiled).
// State a[b][k] = exp(la-c_b): 4 rows x 256 bf16 in LDS, double-buffered,
// row stride RSTR4=272 (A-frag b128 reads land 2 requests/bank = free).
// A row lc reads state row lc&3 (4-way lane broadcast); wave w owns cols
// {32w+2lc, +1}; per-row y-mask freeze (write-old), per-batch power-of-2
// rescale every 8 steps (publish exponent of a[b][0] at T&7==7, apply at
// T&7==0, exact integer accounting in esv), harvest from B1 buffer.
// MFMA: 8 independent depth-2 chains + tree reduce (f32 reassociation only).
// Barrier: fused "s_waitcnt lgkmcnt(0); s_barrier" single asm + sched_barrier.
// Step floor (R11/R12 diagnostics): ~1590 cy = LDS A-delivery (~770, each
// wave ingests 8KB/step — geometry-fixed) + barrier (~350) + compute tail.
// 4-wave variants that would halve the LDS floor NaN'd in two independent
// bisects (R13/R14) — lever abandoned, this shape is the verified optimum.
// ---------------------------------------------------------------------------
#define SCAN_STEP_G(T_, CURE_, NXTE_, EMV_, YV_) do {                         \
  bf8_t Af_[8];                                                               \
  _Pragma("unroll") for (int kk = 0; kk < 8; ++kk)                            \
    Af_[kk] = *(const bf8_t*)&aL[(CURE_) + idxA0 + 32*kk];                    \
  float F0_[4], F1_[4]; int m_[4];                                            \
  _Pragma("unroll") for (int r = 0; r < 4; ++r) {                             \
    m_[r] = YV_[r];                                                           \
    F0_[r] = __expf(EMV_[r].x); F1_[r] = __expf(EMV_[r].y); }                 \
  const int tp_ = ((T_)+4 < S_) ? ((T_)+4) : (S_-1);                          \
  _Pragma("unroll") for (int r = 0; r < 4; ++r) {                             \
    YV_[r] = y[ybase[r] + tp_];                                               \
    EMV_[r] = *(const float2*)&logits[embase_r[r] + (size_t)tp_*256]; }       \
  f4_t c0_[4], c1_[4];                                                        \
  _Pragma("unroll") for (int q = 0; q < 4; ++q) {                             \
    c0_[q] = __builtin_amdgcn_mfma_f32_16x16x32_bf16(Af_[2*q],   Bf0[2*q],   zf4, 0, 0, 0); \
    c0_[q] = __builtin_amdgcn_mfma_f32_16x16x32_bf16(Af_[2*q+1], Bf0[2*q+1], c0_[q], 0, 0, 0); \
    c1_[q] = __builtin_amdgcn_mfma_f32_16x16x32_bf16(Af_[2*q],   Bf1[2*q],   zf4, 0, 0, 0); \
    c1_[q] = __builtin_amdgcn_mfma_f32_16x16x32_bf16(Af_[2*q+1], Bf1[2*q+1], c1_[q], 0, 0, 0); } \
  const f4_t s0_ = (c0_[0] + c0_[1]) + (c0_[2] + c0_[3]);                     \
  const f4_t s1_ = (c1_[0] + c1_[1]) + (c1_[2] + c1_[3]);                     \
  float v0_[4], v1_[4];                                                       \
  _Pragma("unroll") for (int r = 0; r < 4; ++r) {                             \
    v0_[r] = F0_[r]*s0_[r]; v1_[r] = F1_[r]*s1_[r]; }                         \
  if (((T_) & 7) == 0) {                    /* apply rescale published T-1 */ \
    const int4 er_ = *(const int4*)&earr[0];                                  \
    v0_[0] = ldexpf(v0_[0], -er_.x); v1_[0] = ldexpf(v1_[0], -er_.x);         \
    v0_[1] = ldexpf(v0_[1], -er_.y); v1_[1] = ldexpf(v1_[1], -er_.y);         \
    v0_[2] = ldexpf(v0_[2], -er_.z); v1_[2] = ldexpf(v1_[2], -er_.z);         \
    v0_[3] = ldexpf(v0_[3], -er_.w); v1_[3] = ldexpf(v1_[3], -er_.w);         \
    if (w == 0 && l == 0) {                                                   \
      if (m_[0] >= 0) esv[0] += (float)er_.x;                                 \
      if (m_[1] >= 0) esv[1] += (float)er_.y;                                 \
      if (m_[2] >= 0) esv[2] += (float)er_.z;                                 \
      if (m_[3] >= 0) esv[3] += (float)er_.w; } }                             \
  if (lg == 0) {                            /* 16 lanes write 4 rows */       \
    _Pragma("unroll") for (int r = 0; r < 4; ++r) {                           \
      unsigned d_ = pk_bf16(v0_[r], v1_[r]);                                  \
      const unsigned old_ = *(const unsigned*)&aL[(CURE_) + idxW_r[r]];       \
      if (m_[r] < 0) d_ = old_;             /* frozen rows carry exact */     \
      *(unsigned*)&aL[(NXTE_) + idxW_r[r]] = d_; } }                          \
  if (((T_) & 7) == 7 && w == 0 && l == 0) {   /* publish exponent of a[b][0] */ \
    _Pragma("unroll") for (int r = 0; r < 4; ++r)                             \
      earr[r] = (int)((__float_as_uint(v0_[r]) >> 23) & 255) - 127; }         \
  asm volatile("s_waitcnt lgkmcnt(0)\n\ts_barrier" ::: "memory");             \
  __builtin_amdgcn_sched_barrier(0);                                          \
} while (0)

__global__ __launch_bounds__(512, 2) void crf_scan4(
    const float* __restrict__ logits, const float* __restrict__ trans,
    const int* __restrict__ y, float* __restrict__ ws)
{
  __shared__ __align__(16) unsigned short aL[2*BUF4];
  __shared__ __align__(16) int   earr[4];
  __shared__ float esumL[4];
  __shared__ float refL[4];

  const int tid = threadIdx.x;
  const int w  = tid >> 6;        // wave 0..7
  const int l  = tid & 63;
  const int bq = blockIdx.x * 4;
  const int lg = l >> 4;          // lane group 0..3
  const int lc = l & 15;
  const f4_t zf4 = {0.f, 0.f, 0.f, 0.f};

  // ---- B preload (expT cols 32w+2lc, +1), step-invariant, 64 VGPRs
  bf8_t Bf0[8], Bf1[8];
#pragma unroll
  for (int kk = 0; kk < 8; ++kk) {
    bf8_t b0, b1;
    const int n = 32*w + 2*lc;
#pragma unroll
    for (int e = 0; e < 8; ++e) {
      const int k = kk*32 + lg*8 + e;
      b0[e] = (short)f2bf(__expf(trans[k*NT_ + n]));
      b1[e] = (short)f2bf(__expf(trans[k*NT_ + n + 1]));
    }
    Bf0[kk] = b0; Bf1[kk] = b1;
  }

  // ---- address bases (element units)
  const int idxA0 = (lc & 3)*RSTR4 + lg*8;     // A row lc <- state row lc&3 (4-way bcast)
  int idxW_r[4], embase_r[4], ybase[4];
#pragma unroll
  for (int r = 0; r < 4; ++r) {                // batch r == C row (4*lg+r) for all lg
    idxW_r[r]   = r*RSTR4 + 32*w + 2*lc;
    embase_r[r] = (bq + r)*(S_*256) + 32*w + 2*lc;
    ybase[r]    = (bq + r)*S_;
  }

  // ---- init t=0: la0 = logits[:,0,:] + T[START,:]; a0 = exp(la0 - la0[b][0])
  {
    if (tid < 4) {
      refL[tid]  = logits[(size_t)(bq + tid)*(S_*256)] + trans[TG_*NT_];
      esumL[tid] = 0.f;
      earr[tid]  = 0;
    }
    __syncthreads();
    if (tid < 128) {
      const int bi = tid >> 5;          // 4 rows, 32 threads each
      const int cb = (tid & 31) * 8;    // 8 cols per thread
      const float ref = refL[bi];
      uint2 dd;
      {
        const float4 em = *(const float4*)&logits[(size_t)(bq + bi)*(S_*256) + cb];
        const float4 ts = *(const float4*)&trans[TG_*NT_ + cb];
        dd.x = pk_bf16(__expf(em.x + ts.x - ref), __expf(em.y + ts.y - ref));
        dd.y = pk_bf16(__expf(em.z + ts.z - ref), __expf(em.w + ts.w - ref));
      }
      *(uint2*)&aL[bi*RSTR4 + cb] = dd;
      {
        const float4 em = *(const float4*)&logits[(size_t)(bq + bi)*(S_*256) + cb + 4];
        const float4 ts = *(const float4*)&trans[TG_*NT_ + cb + 4];
        dd.x = pk_bf16(__expf(em.x + ts.x - ref), __expf(em.y + ts.y - ref));
        dd.y = pk_bf16(__expf(em.z + ts.z - ref), __expf(em.w + ts.w - ref));
      }
      *(uint2*)&aL[bi*RSTR4 + cb + 4] = dd;
    }
  }

  // ---- prefetch em/y for t = 1..4 (distance-4 pipeline)
  float2 emA[4], emB[4], emC[4], emD[4];
  int yA[4], yB[4], yC[4], yD[4];
#pragma unroll
  for (int r = 0; r < 4; ++r) {
    yA[r] = y[ybase[r] + 1];  emA[r] = *(const float2*)&logits[embase_r[r] + 1*256];
    yB[r] = y[ybase[r] + 2];  emB[r] = *(const float2*)&logits[embase_r[r] + 2*256];
    yC[r] = y[ybase[r] + 3];  emC[r] = *(const float2*)&logits[embase_r[r] + 3*256];
    yD[r] = y[ybase[r] + 4];  emD[r] = *(const float2*)&logits[embase_r[r] + 4*256];
  }
  float esv[4] = {0.f, 0.f, 0.f, 0.f};   // per-batch exponent sums (w0,l0 lane)

  __syncthreads();

#pragma unroll 1
  for (int t = 1; t <= 1017; t += 4) {
    SCAN_STEP_G(t,     0,     BUF4, emA, yA);
    SCAN_STEP_G(t + 1, BUF4,  0,    emB, yB);
    SCAN_STEP_G(t + 2, 0,     BUF4, emC, yC);
    SCAN_STEP_G(t + 3, BUF4,  0,    emD, yD);
  }
  SCAN_STEP_G(1021, 0,    BUF4, emA, yA);
  SCAN_STEP_G(1022, BUF4, 0,    emB, yB);
  SCAN_STEP_G(1023, 0,    BUF4, emC, yC);

  // ---- finalize: log_z[b] = log( sum_j a[b][j]*exp(T[j,END]) ) + esum*ln2 + ref
  if (w == 0 && l == 0) {
#pragma unroll
    for (int r = 0; r < 4; ++r) esumL[r] = esv[r];
  }
  __syncthreads();
  if (tid < 128) {
    const int bi = tid >> 5, j0 = (tid & 31) * 8;
    float p = 0.f;
#pragma unroll
    for (int e = 0; e < 8; ++e) {
      const int k = j0 + e;
      p += bf2f(aL[BUF4 + bi*RSTR4 + k]) * __expf(trans[k*NT_ + 257]);
    }
#pragma unroll
    for (int o = 16; o; o >>= 1) p += __shfl_xor(p, o, 32);
    if ((tid & 31) == 0)
      ws[128 + bq + bi] = __logf(p) + esumL[bi]*LN2f + refL[bi];
  }
}

// ---------------------------------------------------------------------------
// llh (gold-path score) + lengths: 128 blocks x 256 threads, t-parallel.
// ---------------------------------------------------------------------------
__global__ void crf_llh(const float* __restrict__ logits, const float* __restrict__ trans,
                        const int* __restrict__ y, float* __restrict__ ws)
{
  const int b = blockIdx.x, tid = threadIdx.x;
  const int yb = b * S_;
  float part = 0.f; int cnt = 0;
  for (int t = tid; t < S_; t += 256) {
    const int yt = y[yb + t];
    const bool m = (yt >= 0);
    if (m) ++cnt;
    if (t == 0) {
      const int tag0 = m ? yt : 0;
      part += trans[TG_*NT_ + tag0];                       // T[START, y0]
      if (m) part += logits[(size_t)yb * 256 + tag0];
    } else if (m) {
      const int yp = y[yb + t - 1];                        // mask monotone => valid
      part += logits[((size_t)(yb + t)) * 256 + yt] + trans[yp*NT_ + yt];
    }
    if (m && (t + 1 == S_ || y[yb + t + 1] < 0))
      part += trans[yt*NT_ + 257];                         // T[last, END]
  }
#pragma unroll
  for (int o = 32; o; o >>= 1) { part += __shfl_xor(part, o); cnt += __shfl_xor(cnt, o); }
  __shared__ float sp[4]; __shared__ int sc[4];
  if ((tid & 63) == 0) { sp[tid >> 6] = part; sc[tid >> 6] = cnt; }
  __syncthreads();
  if (tid == 0) {
    ws[b]       = sp[0] + sp[1] + sp[2] + sp[3];
    ws[256 + b] = (float)(sc[0] + sc[1] + sc[2] + sc[3]);
  }
}

// ---------------------------------------------------------------------------
// loss = mean_b( -(llh - log_z)/len )
// ---------------------------------------------------------------------------
__global__ void crf_fin(const float* __restrict__ ws, float* __restrict__ out)
{
  const int i = threadIdx.x;  // 128
  float v = -(ws[i] - ws[128 + i]) / ws[256 + i];
#pragma unroll
  for (int o = 32; o; o >>= 1) v += __shfl_xor(v, o);
  __shared__ float s2[2];
  if ((i & 63) == 0) s2[i >> 6] = v;
  __syncthreads();
  if (i == 0) out[0] = (s2[0] + s2[1]) * (1.0f / 128.0f);
}

extern "C" void kernel_launch(void* const* d_in, const int* in_sizes, int n_in,
                              void* d_out, int out_size, void* d_ws, size_t ws_size,
                              hipStream_t stream)
{
  const float* logits = (const float*)d_in[0];
  const float* trans  = (const float*)d_in[1];
  const int*   y      = (const int*)d_in[2];
  float* ws  = (float*)d_ws;   // [0,128) llh | [128,256) log_z | [256,384) len
  float* out = (float*)d_out;

  hipLaunchKernelGGL(crf_llh,   dim3(128), dim3(256), 0, stream, logits, trans, y, ws);
  hipLaunchKernelGGL(crf_scan4, dim3(32),  dim3(512), 0, stream, logits, trans, y, ws);
  hipLaunchKernelGGL(crf_fin,   dim3(1),   dim3(128), 0, stream, ws, out);
}